// Round 2
// baseline (1884.116 us; speedup 1.0000x reference)
//
#include <hip/hip_runtime.h>

// ---------------------------------------------------------------------------
// GNN decoder (MeshGraphNets-style) on MI355X.
// Round 2: inputs/outputs are FP32 (per reference dtypes; round-1 NaN was the
// signature of reading fp32 as bf16). edge_idx is int32. Compute: bf16 MFMA
// with fp32 accum; weights pre-converted to transposed bf16 in ws; LN/bias in
// fp32. d_out = [edge_lat f32 (400000x128) | node_out f32 (50000x3)].
// ws: seg_sum f32[50000*128] @0, cnt f32[50000] @25.6MB, bf16 weightsT after.
// ---------------------------------------------------------------------------

#define N_NODES 50000
#define N_EDGES 400000
#define HID 128
#define LN_EPS 1e-5f

typedef unsigned short u16;
typedef __attribute__((ext_vector_type(8))) short short8;   // 8 x bf16 (4 VGPRs)
typedef __attribute__((ext_vector_type(4))) float floatx4;  // MFMA C/D

#define WPITCH 136  // padded u16 pitch for 128-wide bf16 tiles
#define SYP 129     // padded f32 pitch for y tiles

__device__ __forceinline__ u16 f2bf(float f) {
    union { float f; unsigned int i; } v; v.f = f;
    unsigned int x = v.i;
    return (u16)((x + 0x7FFFu + ((x >> 16) & 1u)) >> 16);  // RNE
}
__device__ __forceinline__ float siluf(float x) { return x * (1.0f / (1.0f + __expf(-x))); }
__device__ __forceinline__ float sigmf(float x) { return 1.0f / (1.0f + __expf(-x)); }

// pack 8 consecutive fp32 into 8 bf16 (uint4)
__device__ __forceinline__ uint4 pack8(const float* p) {
    union { u16 u[8]; uint4 v; } o;
    float4 a = *(const float4*)p;
    float4 b = *(const float4*)(p + 4);
    o.u[0] = f2bf(a.x); o.u[1] = f2bf(a.y); o.u[2] = f2bf(a.z); o.u[3] = f2bf(a.w);
    o.u[4] = f2bf(b.x); o.u[5] = f2bf(b.y); o.u[6] = f2bf(b.z); o.u[7] = f2bf(b.w);
    return o.v;
}

// W fp32 (K x N) row-major -> WT bf16 (N x K) row-major (MFMA B-frags contiguous)
__global__ void k_prepT(const float* __restrict__ src, u16* __restrict__ dst, int K, int N) {
    int i = blockIdx.x * blockDim.x + threadIdx.x;
    if (i < K * N) {
        int k = i / N, n = i - k * N;
        dst[n * K + k] = f2bf(src[i]);
    }
}

// ---------------- Stage 1: edge encoder FFN + LN -> edge_lat (d_out, f32) --
__launch_bounds__(256)
__global__ void k_edge_ee(const float* __restrict__ ef,
                          const float* __restrict__ W1, const float* __restrict__ b1v,
                          const u16* __restrict__ W2T, const float* __restrict__ b2v,
                          const float* __restrict__ g, const float* __restrict__ be,
                          float* __restrict__ outEL) {
    __shared__ __align__(16) u16 sW[128 * WPITCH];   // eeW2T (bf16) resident
    __shared__ __align__(16) u16 sH[16 * WPITCH];
    __shared__ float sY[16 * SYP];
    __shared__ float sRed[16 * 16 * 2];
    __shared__ float sMu[16], sRs[16];
    const int t = threadIdx.x;
    const int lane = t & 63, wave = t >> 6;
    const int mrow = lane & 15, quad = lane >> 4;
    const int eT = t >> 4, cT = t & 15;

    for (int i = t; i < 128 * 16; i += 256) {
        int n = i >> 4, q = i & 15;
        *(uint4*)&sW[n * WPITCH + q * 8] = ((const uint4*)W2T)[i];
    }
    __syncthreads();

    for (int tile = blockIdx.x; tile < N_EDGES / 16; tile += gridDim.x) {
        const int e0 = tile * 16;
        {   // h = silu(ef @ W1 + b1), K=3 via fp32 VALU
            const int e = e0 + eT;
            float f0 = ef[e * 3 + 0], f1 = ef[e * 3 + 1], f2 = ef[e * 3 + 2];
            for (int jj = 0; jj < 8; ++jj) {
                int j = cT * 8 + jj;
                float a = b1v[j] + f0 * W1[j] + f1 * W1[HID + j] + f2 * W1[2 * HID + j];
                sH[eT * WPITCH + j] = f2bf(siluf(a));
            }
        }
        __syncthreads();
        for (int half = 0; half < 2; ++half) {       // y = h @ W2 + b2 via MFMA
            const int nt = wave * 2 + half;
            floatx4 acc = {0.f, 0.f, 0.f, 0.f};
            for (int ks = 0; ks < 4; ++ks) {
                short8 av = *(const short8*)&sH[mrow * WPITCH + ks * 32 + quad * 8];
                short8 bv = *(const short8*)&sW[(nt * 16 + mrow) * WPITCH + ks * 32 + quad * 8];
                acc = __builtin_amdgcn_mfma_f32_16x16x32_bf16(av, bv, acc, 0, 0, 0);
            }
            int n = nt * 16 + mrow;
            float bb = b2v[n];
            for (int r = 0; r < 4; ++r) sY[(quad * 4 + r) * SYP + n] = acc[r] + bb;
        }
        __syncthreads();
        {   // LN partials
            float s = 0.f, s2 = 0.f;
            for (int jj = 0; jj < 8; ++jj) {
                float v = sY[eT * SYP + cT * 8 + jj];
                s += v; s2 += v * v;
            }
            sRed[(eT * 16 + cT) * 2] = s;
            sRed[(eT * 16 + cT) * 2 + 1] = s2;
        }
        __syncthreads();
        if (t < 16) {
            float s = 0.f, s2 = 0.f;
            for (int c = 0; c < 16; ++c) { s += sRed[(t * 16 + c) * 2]; s2 += sRed[(t * 16 + c) * 2 + 1]; }
            float mu = s * (1.0f / HID);
            float var = fmaxf(s2 * (1.0f / HID) - mu * mu, 0.f);
            sMu[t] = mu; sRs[t] = rsqrtf(var + LN_EPS);
        }
        __syncthreads();
        {   // normalize + write fp32 edge_lat
            float mu = sMu[eT], rs = sRs[eT];
            float4 o0, o1;
            float* op = (float*)&o0;
            for (int jj = 0; jj < 8; ++jj) {
                int j = cT * 8 + jj;
                float v = (sY[eT * SYP + j] - mu) * rs * g[j] + be[j];
                if (jj < 4) ((float*)&o0)[jj] = v; else ((float*)&o1)[jj - 4] = v;
            }
            (void)op;
            float* dst = &outEL[(size_t)(e0 + eT) * HID + cT * 8];
            *(float4*)dst = o0;
            *(float4*)(dst + 4) = o1;
        }
        __syncthreads();
    }
}

// ---------------- Stage 2: pe FFN + LN + atomic scatter --------------------
__launch_bounds__(256)
__global__ void k_edge_pe(const int* __restrict__ eidx,
                          const float* __restrict__ nlat, const float* __restrict__ nfeat,
                          const float* __restrict__ el,
                          const u16* __restrict__ W1T, const float* __restrict__ b1v,
                          const u16* __restrict__ W2T, const float* __restrict__ b2v,
                          const float* __restrict__ g, const float* __restrict__ be,
                          float* __restrict__ seg, float* __restrict__ cnt) {
    __shared__ __align__(16) u16 sW2[128 * WPITCH];  // peW2T resident
    __shared__ __align__(16) u16 sA[16 * 392];       // e_in 16x384 bf16 (+pad)
    __shared__ __align__(16) u16 sWk[128 * 40];      // W1T K-chunk (32 wide +pad)
    __shared__ __align__(16) u16 sH[16 * WPITCH];
    __shared__ float sY[16 * SYP];
    __shared__ float sRed[16 * 16 * 2];
    __shared__ float sMu[16], sRs[16];
    __shared__ int sSend[16], sRecv[16];
    const int t = threadIdx.x;
    const int lane = t & 63, wave = t >> 6;
    const int mrow = lane & 15, quad = lane >> 4;
    const int eT = t >> 4, cT = t & 15;

    for (int i = t; i < 128 * 16; i += 256) {
        int n = i >> 4, q = i & 15;
        *(uint4*)&sW2[n * WPITCH + q * 8] = ((const uint4*)W2T)[i];
    }
    __syncthreads();

    for (int tile = blockIdx.x; tile < N_EDGES / 16; tile += gridDim.x) {
        const int e0 = tile * 16;
        if (t < 16) { sSend[t] = eidx[(e0 + t) * 2]; sRecv[t] = eidx[(e0 + t) * 2 + 1]; }
        __syncthreads();
        {   // build A = [sender_lat | receiver_feat | edge_lat], fp32 -> bf16
            int s = sSend[eT], r = sRecv[eT];
            *(uint4*)&sA[eT * 392 + cT * 8]       = pack8(&nlat[(size_t)s * HID + cT * 8]);
            *(uint4*)&sA[eT * 392 + 128 + cT * 8] = pack8(&nfeat[(size_t)r * HID + cT * 8]);
            *(uint4*)&sA[eT * 392 + 256 + cT * 8] = pack8(&el[(size_t)(e0 + eT) * HID + cT * 8]);
        }
        floatx4 acc0 = {0.f,0.f,0.f,0.f}, acc1 = {0.f,0.f,0.f,0.f};
        for (int ks = 0; ks < 12; ++ks) {            // K=384 staged in 32-chunks
            __syncthreads();
            for (int i = t; i < 512; i += 256) {
                int n = i >> 2, q = i & 3;
                *(uint4*)&sWk[n * 40 + q * 8] = *(const uint4*)&W1T[n * 384 + ks * 32 + q * 8];
            }
            __syncthreads();
            short8 av = *(const short8*)&sA[mrow * 392 + ks * 32 + quad * 8];
            short8 bv0 = *(const short8*)&sWk[((wave * 2 + 0) * 16 + mrow) * 40 + quad * 8];
            short8 bv1 = *(const short8*)&sWk[((wave * 2 + 1) * 16 + mrow) * 40 + quad * 8];
            acc0 = __builtin_amdgcn_mfma_f32_16x16x32_bf16(av, bv0, acc0, 0, 0, 0);
            acc1 = __builtin_amdgcn_mfma_f32_16x16x32_bf16(av, bv1, acc1, 0, 0, 0);
        }
        for (int half = 0; half < 2; ++half) {       // silu epilogue -> sH (bf16)
            floatx4 a = half ? acc1 : acc0;
            int n = (wave * 2 + half) * 16 + mrow;
            float bb = b1v[n];
            for (int r = 0; r < 4; ++r) {
                float x = a[r] + bb;
                sH[(quad * 4 + r) * WPITCH + n] = f2bf(siluf(x));
            }
        }
        __syncthreads();
        for (int half = 0; half < 2; ++half) {       // y = h @ W2 + b2
            const int nt = wave * 2 + half;
            floatx4 acc = {0.f,0.f,0.f,0.f};
            for (int ks = 0; ks < 4; ++ks) {
                short8 av = *(const short8*)&sH[mrow * WPITCH + ks * 32 + quad * 8];
                short8 bv = *(const short8*)&sW2[(nt * 16 + mrow) * WPITCH + ks * 32 + quad * 8];
                acc = __builtin_amdgcn_mfma_f32_16x16x32_bf16(av, bv, acc, 0, 0, 0);
            }
            int n = nt * 16 + mrow;
            float bb = b2v[n];
            for (int r = 0; r < 4; ++r) sY[(quad * 4 + r) * SYP + n] = acc[r] + bb;
        }
        __syncthreads();
        {
            float s = 0.f, s2 = 0.f;
            for (int jj = 0; jj < 8; ++jj) {
                float v = sY[eT * SYP + cT * 8 + jj];
                s += v; s2 += v * v;
            }
            sRed[(eT * 16 + cT) * 2] = s;
            sRed[(eT * 16 + cT) * 2 + 1] = s2;
        }
        __syncthreads();
        if (t < 16) {
            float s = 0.f, s2 = 0.f;
            for (int c = 0; c < 16; ++c) { s += sRed[(t * 16 + c) * 2]; s2 += sRed[(t * 16 + c) * 2 + 1]; }
            float mu = s * (1.0f / HID);
            float var = fmaxf(s2 * (1.0f / HID) - mu * mu, 0.f);
            sMu[t] = mu; sRs[t] = rsqrtf(var + LN_EPS);
        }
        __syncthreads();
        {   // LN + fp32 scatter-add (new_edge itself is not an output)
            float mu = sMu[eT], rs = sRs[eT];
            int r = sRecv[eT];
            for (int jj = 0; jj < 8; ++jj) {
                int j = cT * 8 + jj;
                float v = (sY[eT * SYP + j] - mu) * rs * g[j] + be[j];
                atomicAdd(&seg[(size_t)r * HID + j], v);
            }
        }
        if (t < 16) atomicAdd(&cnt[sRecv[t]], 1.0f);
        __syncthreads();
    }
}

// ---------------- Stage 3: node FFNs (pn + no) -----------------------------
__launch_bounds__(256)
__global__ void k_node(const float* __restrict__ nfeat,
                       const float* __restrict__ seg, const float* __restrict__ cnt,
                       const u16* __restrict__ W1T, const float* __restrict__ b1v,
                       const u16* __restrict__ W2T, const float* __restrict__ b2v,
                       const float* __restrict__ g, const float* __restrict__ be,
                       const u16* __restrict__ noW1T, const float* __restrict__ nob1,
                       const float* __restrict__ noW2, const float* __restrict__ nob2,
                       float* __restrict__ outN) {
    __shared__ __align__(16) u16 sW2[128 * WPITCH];  // pnW2T resident
    __shared__ __align__(16) u16 sA[16 * 264];       // n_in 16x256 bf16 (+pad)
    __shared__ __align__(16) u16 sWk[128 * 40];
    __shared__ __align__(16) u16 sH[16 * WPITCH];
    __shared__ float sY[16 * SYP];
    __shared__ float sRed[16 * 16 * 2];
    __shared__ float sMu[16], sRs[16];
    const int t = threadIdx.x;
    const int lane = t & 63, wave = t >> 6;
    const int mrow = lane & 15, quad = lane >> 4;
    const int eT = t >> 4, cT = t & 15;

    for (int i = t; i < 128 * 16; i += 256) {
        int n = i >> 4, q = i & 15;
        *(uint4*)&sW2[n * WPITCH + q * 8] = ((const uint4*)W2T)[i];
    }
    __syncthreads();

    for (int tile = blockIdx.x; tile < N_NODES / 16; tile += gridDim.x) {
        const int n0 = tile * 16;
        {   // A = [node_features | mean_edges] fp32 -> bf16
            int node = n0 + eT;
            *(uint4*)&sA[eT * 264 + cT * 8] = pack8(&nfeat[(size_t)node * HID + cT * 8]);
            float inv = 1.0f / fmaxf(cnt[node], 1.0f);
            union { u16 u[8]; uint4 v; } o;
            for (int jj = 0; jj < 8; ++jj)
                o.u[jj] = f2bf(seg[(size_t)node * HID + cT * 8 + jj] * inv);
            *(uint4*)&sA[eT * 264 + 128 + cT * 8] = o.v;
        }
        floatx4 acc0 = {0.f,0.f,0.f,0.f}, acc1 = {0.f,0.f,0.f,0.f};
        for (int ks = 0; ks < 8; ++ks) {             // K=256
            __syncthreads();
            for (int i = t; i < 512; i += 256) {
                int n = i >> 2, q = i & 3;
                *(uint4*)&sWk[n * 40 + q * 8] = *(const uint4*)&W1T[n * 256 + ks * 32 + q * 8];
            }
            __syncthreads();
            short8 av = *(const short8*)&sA[mrow * 264 + ks * 32 + quad * 8];
            short8 bv0 = *(const short8*)&sWk[((wave * 2 + 0) * 16 + mrow) * 40 + quad * 8];
            short8 bv1 = *(const short8*)&sWk[((wave * 2 + 1) * 16 + mrow) * 40 + quad * 8];
            acc0 = __builtin_amdgcn_mfma_f32_16x16x32_bf16(av, bv0, acc0, 0, 0, 0);
            acc1 = __builtin_amdgcn_mfma_f32_16x16x32_bf16(av, bv1, acc1, 0, 0, 0);
        }
        for (int half = 0; half < 2; ++half) {
            floatx4 a = half ? acc1 : acc0;
            int n = (wave * 2 + half) * 16 + mrow;
            float bb = b1v[n];
            for (int r = 0; r < 4; ++r) {
                float x = a[r] + bb;
                sH[(quad * 4 + r) * WPITCH + n] = f2bf(siluf(x));
            }
        }
        __syncthreads();
        for (int half = 0; half < 2; ++half) {       // y = h @ pnW2 + b2
            const int nt = wave * 2 + half;
            floatx4 acc = {0.f,0.f,0.f,0.f};
            for (int ks = 0; ks < 4; ++ks) {
                short8 av = *(const short8*)&sH[mrow * WPITCH + ks * 32 + quad * 8];
                short8 bv = *(const short8*)&sW2[(nt * 16 + mrow) * WPITCH + ks * 32 + quad * 8];
                acc = __builtin_amdgcn_mfma_f32_16x16x32_bf16(av, bv, acc, 0, 0, 0);
            }
            int n = nt * 16 + mrow;
            float bb = b2v[n];
            for (int r = 0; r < 4; ++r) sY[(quad * 4 + r) * SYP + n] = acc[r] + bb;
        }
        __syncthreads();
        {
            float s = 0.f, s2 = 0.f;
            for (int jj = 0; jj < 8; ++jj) {
                float v = sY[eT * SYP + cT * 8 + jj];
                s += v; s2 += v * v;
            }
            sRed[(eT * 16 + cT) * 2] = s;
            sRed[(eT * 16 + cT) * 2 + 1] = s2;
        }
        __syncthreads();
        if (t < 16) {
            float s = 0.f, s2 = 0.f;
            for (int c = 0; c < 16; ++c) { s += sRed[(t * 16 + c) * 2]; s2 += sRed[(t * 16 + c) * 2 + 1]; }
            float mu = s * (1.0f / HID);
            float var = fmaxf(s2 * (1.0f / HID) - mu * mu, 0.f);
            sMu[t] = mu; sRs[t] = rsqrtf(var + LN_EPS);
        }
        __syncthreads();
        {   // new_node (LN output) -> sH bf16 as A-operand for the no-FFN
            float mu = sMu[eT], rs = sRs[eT];
            for (int jj = 0; jj < 8; ++jj) {
                int j = cT * 8 + jj;
                sH[eT * WPITCH + j] = f2bf((sY[eT * SYP + j] - mu) * rs * g[j] + be[j]);
            }
        }
        __syncthreads();
        for (int half = 0; half < 2; ++half) {       // h3 = sigmoid(new_node @ noW1 + b1)
            const int nt = wave * 2 + half;
            floatx4 acc = {0.f,0.f,0.f,0.f};
            for (int ks = 0; ks < 4; ++ks) {
                short8 av = *(const short8*)&sH[mrow * WPITCH + ks * 32 + quad * 8];
                short8 bv = *(const short8*)&noW1T[(nt * 16 + mrow) * HID + ks * 32 + quad * 8];
                acc = __builtin_amdgcn_mfma_f32_16x16x32_bf16(av, bv, acc, 0, 0, 0);
            }
            int n = nt * 16 + mrow;
            float bb = nob1[n];
            for (int r = 0; r < 4; ++r) sY[(quad * 4 + r) * SYP + n] = sigmf(acc[r] + bb);
        }
        __syncthreads();
        if (t < 48) {                                // out = h3 @ noW2 + b2 (N=3), fp32 VALU
            int ni = t / 3, c = t - ni * 3;
            float s = nob2[c];
            for (int k = 0; k < HID; ++k) s += sY[ni * SYP + k] * noW2[k * 3 + c];
            outN[(size_t)(n0 + ni) * 3 + c] = s;
        }
        __syncthreads();
    }
}

extern "C" void kernel_launch(void* const* d_in, const int* in_sizes, int n_in,
                              void* d_out, int out_size, void* d_ws, size_t ws_size,
                              hipStream_t stream) {
    const int*   eidx  = (const int*)d_in[0];
    const float* ef    = (const float*)d_in[1];
    const float* nlat  = (const float*)d_in[2];
    const float* nfeat = (const float*)d_in[3];
    const float* eeW1 = (const float*)d_in[4];
    const float* eeb1 = (const float*)d_in[5];
    const float* eeW2 = (const float*)d_in[6];
    const float* eeb2 = (const float*)d_in[7];
    const float* eeg  = (const float*)d_in[8];
    const float* eebe = (const float*)d_in[9];
    const float* peW1 = (const float*)d_in[10];
    const float* peb1 = (const float*)d_in[11];
    const float* peW2 = (const float*)d_in[12];
    const float* peb2 = (const float*)d_in[13];
    const float* peg  = (const float*)d_in[14];
    const float* pebe = (const float*)d_in[15];
    const float* pnW1 = (const float*)d_in[16];
    const float* pnb1 = (const float*)d_in[17];
    const float* pnW2 = (const float*)d_in[18];
    const float* pnb2 = (const float*)d_in[19];
    const float* png_ = (const float*)d_in[20];
    const float* pnbe = (const float*)d_in[21];
    const float* noW1 = (const float*)d_in[22];
    const float* nob1 = (const float*)d_in[23];
    const float* noW2 = (const float*)d_in[24];
    const float* nob2 = (const float*)d_in[25];

    char* ws = (char*)d_ws;
    float* seg = (float*)ws;                                  // 25,600,000 B
    float* cnt = (float*)(ws + 25600000);                     //    200,000 B
    u16* eeW2T = (u16*)(ws + 25800000);
    u16* peW1T = (u16*)(ws + 25800000 + 32768);
    u16* peW2T = (u16*)(ws + 25800000 + 32768 + 98304);
    u16* pnW1T = (u16*)(ws + 25800000 + 32768 + 98304 + 32768);
    u16* pnW2T = (u16*)(ws + 25800000 + 32768 + 98304 + 32768 + 65536);
    u16* noW1T = (u16*)(ws + 25800000 + 32768 + 98304 + 32768 + 65536 + 32768);

    hipMemsetAsync(ws, 0, 25800000, stream);  // zero seg_sum + cnt

    k_prepT<<<64, 256, 0, stream>>>(eeW2, eeW2T, 128, 128);
    k_prepT<<<192, 256, 0, stream>>>(peW1, peW1T, 384, 128);
    k_prepT<<<64, 256, 0, stream>>>(peW2, peW2T, 128, 128);
    k_prepT<<<128, 256, 0, stream>>>(pnW1, pnW1T, 256, 128);
    k_prepT<<<64, 256, 0, stream>>>(pnW2, pnW2T, 128, 128);
    k_prepT<<<64, 256, 0, stream>>>(noW1, noW1T, 128, 128);

    float* outEL = (float*)d_out;
    float* outN  = outEL + (size_t)N_EDGES * HID;

    k_edge_ee<<<768, 256, 0, stream>>>(ef, eeW1, eeb1, eeW2T, eeb2, eeg, eebe, outEL);
    k_edge_pe<<<512, 256, 0, stream>>>(eidx, nlat, nfeat, outEL, peW1T, peb1, peW2T, peb2,
                                       peg, pebe, seg, cnt);
    k_node<<<512, 256, 0, stream>>>(nfeat, seg, cnt, pnW1T, pnb1, pnW2T, pnb2, png_, pnbe,
                                    noW1T, nob1, noW2, nob2, outN);
}

// Round 4
// 863.861 us; speedup vs baseline: 2.1810x; 2.1810x over previous
//
#include <hip/hip_runtime.h>

// ---------------------------------------------------------------------------
// Round 4: round-3 structure with the ee staging bug fixed (sW1 was only
// loaded for t<256 of 384 elements -> f2 row garbage -> absmax 6.4).
//  - pe: M=64 tiles, A-frags gathered straight into registers, W1/W2
//    double-buffered 32-K chunks, per-wave LDS transpose for h, LN via quad
//    shuffles, f32 atomic scatter.
//  - ee: weights LDS-resident, zero barriers in tile loop.
//  - node: same pattern, noW1 resident, 50000%64 tail masked.
// ---------------------------------------------------------------------------

#define N_NODES 50000
#define N_EDGES 400000
#define HID 128
#define LN_EPS 1e-5f

typedef unsigned short u16;
typedef __attribute__((ext_vector_type(8))) short short8;   // 8 x bf16
typedef __attribute__((ext_vector_type(4))) float floatx4;  // MFMA C/D

__device__ __forceinline__ u16 f2bf(float f) {
    union { float f; unsigned int i; } v; v.f = f;
    unsigned int x = v.i;
    return (u16)((x + 0x7FFFu + ((x >> 16) & 1u)) >> 16);  // RNE
}
__device__ __forceinline__ float siluf(float x) { return x * (1.0f / (1.0f + __expf(-x))); }
__device__ __forceinline__ float sigmf(float x) { return 1.0f / (1.0f + __expf(-x)); }

__device__ __forceinline__ short8 pack8(const float* __restrict__ p) {
    union { u16 u[8]; short8 v; } o;
    float4 a = *(const float4*)p;
    float4 b = *(const float4*)(p + 4);
    o.u[0] = f2bf(a.x); o.u[1] = f2bf(a.y); o.u[2] = f2bf(a.z); o.u[3] = f2bf(a.w);
    o.u[4] = f2bf(b.x); o.u[5] = f2bf(b.y); o.u[6] = f2bf(b.z); o.u[7] = f2bf(b.w);
    return o.v;
}
__device__ __forceinline__ short8 pack8s(const float* __restrict__ p, float sc) {
    union { u16 u[8]; short8 v; } o;
    float4 a = *(const float4*)p;
    float4 b = *(const float4*)(p + 4);
    o.u[0] = f2bf(a.x * sc); o.u[1] = f2bf(a.y * sc); o.u[2] = f2bf(a.z * sc); o.u[3] = f2bf(a.w * sc);
    o.u[4] = f2bf(b.x * sc); o.u[5] = f2bf(b.y * sc); o.u[6] = f2bf(b.z * sc); o.u[7] = f2bf(b.w * sc);
    return o.v;
}

// W fp32 (K x N) row-major -> WT bf16 (N x K) row-major
__global__ void k_prepT(const float* __restrict__ src, u16* __restrict__ dst, int K, int N) {
    int i = blockIdx.x * blockDim.x + threadIdx.x;
    if (i < K * N) {
        int k = i / N, n = i - k * N;
        dst[n * K + k] = f2bf(src[i]);
    }
}

// ---------------- Stage 1: ee FFN + LN -> edge_lat (zero-barrier loop) -----
__launch_bounds__(256)
__global__ void k_edge_ee(const float* __restrict__ ef,
                          const float* __restrict__ W1, const float* __restrict__ b1v,
                          const u16* __restrict__ W2T, const float* __restrict__ b2v,
                          const float* __restrict__ g, const float* __restrict__ be,
                          float* __restrict__ outEL) {
    __shared__ __align__(16) u16 sW2[128 * 136];
    __shared__ float sW1[384];
    __shared__ float sB1[128];
    const int t = threadIdx.x;
    const int lane = t & 63, w = t >> 6;
    const int l15 = lane & 15, quad = lane >> 4;

    for (int i = t; i < 2048; i += 256) {
        int n = i >> 4, q = i & 15;
        *(uint4*)&sW2[n * 136 + q * 8] = *(const uint4*)&W2T[n * 128 + q * 8];
    }
    for (int i = t; i < 384; i += 256) sW1[i] = W1[i];   // FIX: was `if (t<384)`
    if (t < 128) sB1[t] = b1v[t];
    __syncthreads();

    float b2r[8], gr[8], ber[8];
    #pragma unroll
    for (int nt = 0; nt < 8; ++nt) {
        int col = nt * 16 + l15;
        b2r[nt] = b2v[col]; gr[nt] = g[col]; ber[nt] = be[col];
    }

    for (int tile = blockIdx.x; tile < N_EDGES / 64; tile += gridDim.x) {
        const int e0 = tile * 64;
        const int em = e0 + w * 16 + l15;
        float f0 = ef[em * 3 + 0], f1 = ef[em * 3 + 1], f2 = ef[em * 3 + 2];
        short8 ha[4];
        #pragma unroll
        for (int ks = 0; ks < 4; ++ks) {          // h directly in A-frag layout
            union { u16 u[8]; short8 v; } hh;
            #pragma unroll
            for (int jj = 0; jj < 8; ++jj) {
                int j = ks * 32 + quad * 8 + jj;
                float x = sB1[j] + f0 * sW1[j] + f1 * sW1[128 + j] + f2 * sW1[256 + j];
                hh.u[jj] = f2bf(siluf(x));
            }
            ha[ks] = hh.v;
        }
        floatx4 acc[8];
        #pragma unroll
        for (int nt = 0; nt < 8; ++nt) acc[nt] = (floatx4){0.f, 0.f, 0.f, 0.f};
        #pragma unroll
        for (int ks = 0; ks < 4; ++ks) {
            #pragma unroll
            for (int nt = 0; nt < 8; ++nt) {
                short8 bv = *(const short8*)&sW2[(nt * 16 + l15) * 136 + ks * 32 + quad * 8];
                acc[nt] = __builtin_amdgcn_mfma_f32_16x16x32_bf16(ha[ks], bv, acc[nt], 0, 0, 0);
            }
        }
        float sum[4] = {0, 0, 0, 0}, sq[4] = {0, 0, 0, 0};
        #pragma unroll
        for (int nt = 0; nt < 8; ++nt)
            #pragma unroll
            for (int rr = 0; rr < 4; ++rr) {
                float v = acc[nt][rr] + b2r[nt];
                acc[nt][rr] = v; sum[rr] += v; sq[rr] += v * v;
            }
        #pragma unroll
        for (int m = 1; m < 16; m <<= 1)
            #pragma unroll
            for (int rr = 0; rr < 4; ++rr) {
                sum[rr] += __shfl_xor(sum[rr], m);
                sq[rr]  += __shfl_xor(sq[rr], m);
            }
        float mu[4], rs[4];
        #pragma unroll
        for (int rr = 0; rr < 4; ++rr) {
            mu[rr] = sum[rr] * (1.0f / HID);
            float var = fmaxf(sq[rr] * (1.0f / HID) - mu[rr] * mu[rr], 0.f);
            rs[rr] = rsqrtf(var + LN_EPS);
        }
        #pragma unroll
        for (int nt = 0; nt < 8; ++nt) {
            int col = nt * 16 + l15;
            #pragma unroll
            for (int rr = 0; rr < 4; ++rr) {
                int row = e0 + w * 16 + quad * 4 + rr;
                outEL[(size_t)row * HID + col] = (acc[nt][rr] - mu[rr]) * rs[rr] * gr[nt] + ber[nt];
            }
        }
    }
}

// ---------------- Stage 2: pe FFN + LN + atomic scatter --------------------
__launch_bounds__(256)
__global__ void k_edge_pe(const int* __restrict__ eidx,
                          const float* __restrict__ nlat, const float* __restrict__ nfeat,
                          const float* __restrict__ el,
                          const u16* __restrict__ W1T, const float* __restrict__ b1v,
                          const u16* __restrict__ W2T, const float* __restrict__ b2v,
                          const float* __restrict__ g, const float* __restrict__ be,
                          float* __restrict__ seg, float* __restrict__ cnt) {
    __shared__ __align__(16) u16 sWk[2][128 * 40];   // 32-K weight chunks (dbuf)
    __shared__ __align__(16) u16 sH[4][16 * 136];    // per-wave h transpose
    __shared__ int sRecv[64];
    const int t = threadIdx.x;
    const int lane = t & 63, w = t >> 6;
    const int l15 = lane & 15, quad = lane >> 4;

    float b1r[8], b2r[8], gr[8], ber[8];
    #pragma unroll
    for (int nt = 0; nt < 8; ++nt) {
        int col = nt * 16 + l15;
        b1r[nt] = b1v[col]; b2r[nt] = b2v[col]; gr[nt] = g[col]; ber[nt] = be[col];
    }

    for (int tile = blockIdx.x; tile < N_EDGES / 64; tile += gridDim.x) {
        const int e0 = tile * 64;
        __syncthreads();                              // protect sWk/sH/sRecv reuse
        if (t < 64) sRecv[t] = eidx[(e0 + t) * 2 + 1];
        const int em = e0 + w * 16 + l15;
        const int snd = eidx[em * 2], rcv = eidx[em * 2 + 1];
        short8 a[12];                                 // A-frags straight to regs
        #pragma unroll
        for (int ks = 0; ks < 4; ++ks) {
            a[ks]     = pack8(&nlat[(size_t)snd * HID + ks * 32 + quad * 8]);
            a[4 + ks] = pack8(&nfeat[(size_t)rcv * HID + ks * 32 + quad * 8]);
            a[8 + ks] = pack8(&el[(size_t)em * HID + ks * 32 + quad * 8]);
        }
        #pragma unroll
        for (int i = t; i < 512; i += 256) {          // stage W1 chunk 0
            int n = i >> 2, q = i & 3;
            *(uint4*)&sWk[0][n * 40 + q * 8] = *(const uint4*)&W1T[n * 384 + q * 8];
        }
        __syncthreads();
        floatx4 acc[8];
        #pragma unroll
        for (int nt = 0; nt < 8; ++nt) acc[nt] = (floatx4){0.f, 0.f, 0.f, 0.f};
        #pragma unroll
        for (int ks = 0; ks < 12; ++ks) {             // K=384, dbuf chunks
            if (ks < 11) {
                #pragma unroll
                for (int i = t; i < 512; i += 256) {
                    int n = i >> 2, q = i & 3;
                    *(uint4*)&sWk[(ks + 1) & 1][n * 40 + q * 8] =
                        *(const uint4*)&W1T[n * 384 + (ks + 1) * 32 + q * 8];
                }
            }
            const u16* B = sWk[ks & 1];
            #pragma unroll
            for (int nt = 0; nt < 8; ++nt) {
                short8 bv = *(const short8*)&B[(nt * 16 + l15) * 40 + quad * 8];
                acc[nt] = __builtin_amdgcn_mfma_f32_16x16x32_bf16(a[ks], bv, acc[nt], 0, 0, 0);
            }
            __syncthreads();
        }
        // h = silu(acc+b1) -> sH[w] transposed; stage W2 chunk 0
        #pragma unroll
        for (int nt = 0; nt < 8; ++nt) {
            int col = nt * 16 + l15;
            #pragma unroll
            for (int rr = 0; rr < 4; ++rr)
                sH[w][(quad * 4 + rr) * 136 + col] = f2bf(siluf(acc[nt][rr] + b1r[nt]));
        }
        #pragma unroll
        for (int i = t; i < 512; i += 256) {
            int n = i >> 2, q = i & 3;
            *(uint4*)&sWk[0][n * 40 + q * 8] = *(const uint4*)&W2T[n * 128 + q * 8];
        }
        __syncthreads();
        short8 ha[4];
        #pragma unroll
        for (int ks = 0; ks < 4; ++ks)
            ha[ks] = *(const short8*)&sH[w][l15 * 136 + ks * 32 + quad * 8];
        floatx4 acc2[8];
        #pragma unroll
        for (int nt = 0; nt < 8; ++nt) acc2[nt] = (floatx4){0.f, 0.f, 0.f, 0.f};
        #pragma unroll
        for (int ks = 0; ks < 4; ++ks) {              // K=128 over h
            if (ks < 3) {
                #pragma unroll
                for (int i = t; i < 512; i += 256) {
                    int n = i >> 2, q = i & 3;
                    *(uint4*)&sWk[(ks + 1) & 1][n * 40 + q * 8] =
                        *(const uint4*)&W2T[n * 128 + (ks + 1) * 32 + q * 8];
                }
            }
            const u16* B = sWk[ks & 1];
            #pragma unroll
            for (int nt = 0; nt < 8; ++nt) {
                short8 bv = *(const short8*)&B[(nt * 16 + l15) * 40 + quad * 8];
                acc2[nt] = __builtin_amdgcn_mfma_f32_16x16x32_bf16(ha[ks], bv, acc2[nt], 0, 0, 0);
            }
            if (ks < 3) __syncthreads();
        }
        // LN + atomic scatter
        float sum[4] = {0, 0, 0, 0}, sq[4] = {0, 0, 0, 0};
        #pragma unroll
        for (int nt = 0; nt < 8; ++nt)
            #pragma unroll
            for (int rr = 0; rr < 4; ++rr) {
                float v = acc2[nt][rr] + b2r[nt];
                acc2[nt][rr] = v; sum[rr] += v; sq[rr] += v * v;
            }
        #pragma unroll
        for (int m = 1; m < 16; m <<= 1)
            #pragma unroll
            for (int rr = 0; rr < 4; ++rr) {
                sum[rr] += __shfl_xor(sum[rr], m);
                sq[rr]  += __shfl_xor(sq[rr], m);
            }
        float mu[4], rs[4];
        int rrow[4];
        #pragma unroll
        for (int rr = 0; rr < 4; ++rr) {
            mu[rr] = sum[rr] * (1.0f / HID);
            float var = fmaxf(sq[rr] * (1.0f / HID) - mu[rr] * mu[rr], 0.f);
            rs[rr] = rsqrtf(var + LN_EPS);
            rrow[rr] = sRecv[w * 16 + quad * 4 + rr];
        }
        #pragma unroll
        for (int nt = 0; nt < 8; ++nt) {
            int col = nt * 16 + l15;
            #pragma unroll
            for (int rr = 0; rr < 4; ++rr) {
                float v = (acc2[nt][rr] - mu[rr]) * rs[rr] * gr[nt] + ber[nt];
                atomicAdd(&seg[(size_t)rrow[rr] * HID + col], v);
            }
        }
        if (t < 64) atomicAdd(&cnt[sRecv[t]], 1.0f);
    }
}

// ---------------- Stage 3: node FFNs (pn + no) -----------------------------
__launch_bounds__(256)
__global__ void k_node(const float* __restrict__ nfeat,
                       const float* __restrict__ seg, const float* __restrict__ cnt,
                       const u16* __restrict__ W1T, const float* __restrict__ b1v,
                       const u16* __restrict__ W2T, const float* __restrict__ b2v,
                       const float* __restrict__ g, const float* __restrict__ be,
                       const u16* __restrict__ noW1T, const float* __restrict__ nob1,
                       const float* __restrict__ noW2, const float* __restrict__ nob2,
                       float* __restrict__ outN) {
    __shared__ __align__(16) u16 sWk[2][128 * 40];
    __shared__ __align__(16) u16 sH[4][16 * 136];
    __shared__ __align__(16) u16 sNo[128 * 136];     // noW1T resident
    const int t = threadIdx.x;
    const int lane = t & 63, w = t >> 6;
    const int l15 = lane & 15, quad = lane >> 4;

    for (int i = t; i < 2048; i += 256) {
        int n = i >> 4, q = i & 15;
        *(uint4*)&sNo[n * 136 + q * 8] = *(const uint4*)&noW1T[n * 128 + q * 8];
    }
    float b1r[8], b2r[8], gr[8], ber[8], nob1r[8], w2r[8][3];
    #pragma unroll
    for (int nt = 0; nt < 8; ++nt) {
        int col = nt * 16 + l15;
        b1r[nt] = b1v[col]; b2r[nt] = b2v[col]; gr[nt] = g[col]; ber[nt] = be[col];
        nob1r[nt] = nob1[col];
        #pragma unroll
        for (int c = 0; c < 3; ++c) w2r[nt][c] = noW2[col * 3 + c];
    }
    float nob2r[3] = {nob2[0], nob2[1], nob2[2]};
    __syncthreads();

    const int NT = (N_NODES + 63) / 64;
    for (int tile = blockIdx.x; tile < NT; tile += gridDim.x) {
        const int n0 = tile * 64;
        __syncthreads();
        const int node = n0 + w * 16 + l15;
        const bool valid = node < N_NODES;
        const int nc = valid ? node : 0;
        float inv = 1.0f / fmaxf(cnt[nc], 1.0f);
        short8 a[8];
        #pragma unroll
        for (int ks = 0; ks < 4; ++ks) {
            a[ks]     = pack8(&nfeat[(size_t)nc * HID + ks * 32 + quad * 8]);
            a[4 + ks] = pack8s(&seg[(size_t)nc * HID + ks * 32 + quad * 8], inv);
        }
        #pragma unroll
        for (int i = t; i < 512; i += 256) {
            int n = i >> 2, q = i & 3;
            *(uint4*)&sWk[0][n * 40 + q * 8] = *(const uint4*)&W1T[n * 256 + q * 8];
        }
        __syncthreads();
        floatx4 acc[8];
        #pragma unroll
        for (int nt = 0; nt < 8; ++nt) acc[nt] = (floatx4){0.f, 0.f, 0.f, 0.f};
        #pragma unroll
        for (int ks = 0; ks < 8; ++ks) {              // K=256
            if (ks < 7) {
                #pragma unroll
                for (int i = t; i < 512; i += 256) {
                    int n = i >> 2, q = i & 3;
                    *(uint4*)&sWk[(ks + 1) & 1][n * 40 + q * 8] =
                        *(const uint4*)&W1T[n * 256 + (ks + 1) * 32 + q * 8];
                }
            }
            const u16* B = sWk[ks & 1];
            #pragma unroll
            for (int nt = 0; nt < 8; ++nt) {
                short8 bv = *(const short8*)&B[(nt * 16 + l15) * 40 + quad * 8];
                acc[nt] = __builtin_amdgcn_mfma_f32_16x16x32_bf16(a[ks], bv, acc[nt], 0, 0, 0);
            }
            __syncthreads();
        }
        #pragma unroll
        for (int nt = 0; nt < 8; ++nt) {              // silu -> sH[w]
            int col = nt * 16 + l15;
            #pragma unroll
            for (int rr = 0; rr < 4; ++rr)
                sH[w][(quad * 4 + rr) * 136 + col] = f2bf(siluf(acc[nt][rr] + b1r[nt]));
        }
        #pragma unroll
        for (int i = t; i < 512; i += 256) {
            int n = i >> 2, q = i & 3;
            *(uint4*)&sWk[0][n * 40 + q * 8] = *(const uint4*)&W2T[n * 128 + q * 8];
        }
        __syncthreads();
        short8 ha[4];
        #pragma unroll
        for (int ks = 0; ks < 4; ++ks)
            ha[ks] = *(const short8*)&sH[w][l15 * 136 + ks * 32 + quad * 8];
        floatx4 acc2[8];
        #pragma unroll
        for (int nt = 0; nt < 8; ++nt) acc2[nt] = (floatx4){0.f, 0.f, 0.f, 0.f};
        #pragma unroll
        for (int ks = 0; ks < 4; ++ks) {              // y = h @ pnW2
            if (ks < 3) {
                #pragma unroll
                for (int i = t; i < 512; i += 256) {
                    int n = i >> 2, q = i & 3;
                    *(uint4*)&sWk[(ks + 1) & 1][n * 40 + q * 8] =
                        *(const uint4*)&W2T[n * 128 + (ks + 1) * 32 + q * 8];
                }
            }
            const u16* B = sWk[ks & 1];
            #pragma unroll
            for (int nt = 0; nt < 8; ++nt) {
                short8 bv = *(const short8*)&B[(nt * 16 + l15) * 40 + quad * 8];
                acc2[nt] = __builtin_amdgcn_mfma_f32_16x16x32_bf16(ha[ks], bv, acc2[nt], 0, 0, 0);
            }
            if (ks < 3) __syncthreads();
        }
        // LN -> new_node (bf16) -> sH[w]
        float sum[4] = {0, 0, 0, 0}, sq[4] = {0, 0, 0, 0};
        #pragma unroll
        for (int nt = 0; nt < 8; ++nt)
            #pragma unroll
            for (int rr = 0; rr < 4; ++rr) {
                float v = acc2[nt][rr] + b2r[nt];
                acc2[nt][rr] = v; sum[rr] += v; sq[rr] += v * v;
            }
        #pragma unroll
        for (int m = 1; m < 16; m <<= 1)
            #pragma unroll
            for (int rr = 0; rr < 4; ++rr) {
                sum[rr] += __shfl_xor(sum[rr], m);
                sq[rr]  += __shfl_xor(sq[rr], m);
            }
        #pragma unroll
        for (int nt = 0; nt < 8; ++nt) {
            int col = nt * 16 + l15;
            #pragma unroll
            for (int rr = 0; rr < 4; ++rr) {
                float mu = sum[rr] * (1.0f / HID);
                float var = fmaxf(sq[rr] * (1.0f / HID) - mu * mu, 0.f);
                float rsn = rsqrtf(var + LN_EPS);
                sH[w][(quad * 4 + rr) * 136 + col] =
                    f2bf((acc2[nt][rr] - mu) * rsn * gr[nt] + ber[nt]);
            }
        }
        __syncthreads();
        short8 h2[4];
        #pragma unroll
        for (int ks = 0; ks < 4; ++ks)
            h2[ks] = *(const short8*)&sH[w][l15 * 136 + ks * 32 + quad * 8];
        floatx4 acc3[8];
        #pragma unroll
        for (int nt = 0; nt < 8; ++nt) acc3[nt] = (floatx4){0.f, 0.f, 0.f, 0.f};
        #pragma unroll
        for (int ks = 0; ks < 4; ++ks) {              // h3 = new_node @ noW1 (resident)
            #pragma unroll
            for (int nt = 0; nt < 8; ++nt) {
                short8 bv = *(const short8*)&sNo[(nt * 16 + l15) * 136 + ks * 32 + quad * 8];
                acc3[nt] = __builtin_amdgcn_mfma_f32_16x16x32_bf16(h2[ks], bv, acc3[nt], 0, 0, 0);
            }
        }
        float p[4][3] = {{0,0,0},{0,0,0},{0,0,0},{0,0,0}};
        #pragma unroll
        for (int nt = 0; nt < 8; ++nt)
            #pragma unroll
            for (int rr = 0; rr < 4; ++rr) {
                float h3 = sigmf(acc3[nt][rr] + nob1r[nt]);
                #pragma unroll
                for (int c = 0; c < 3; ++c) p[rr][c] += h3 * w2r[nt][c];
            }
        #pragma unroll
        for (int m = 1; m < 16; m <<= 1)
            #pragma unroll
            for (int rr = 0; rr < 4; ++rr)
                #pragma unroll
                for (int c = 0; c < 3; ++c) p[rr][c] += __shfl_xor(p[rr][c], m);
        if (l15 < 3) {
            #pragma unroll
            for (int rr = 0; rr < 4; ++rr) {
                int row = n0 + w * 16 + quad * 4 + rr;
                if (row < N_NODES) outN[(size_t)row * 3 + l15] = p[rr][l15] + nob2r[l15];
            }
        }
    }
}

extern "C" void kernel_launch(void* const* d_in, const int* in_sizes, int n_in,
                              void* d_out, int out_size, void* d_ws, size_t ws_size,
                              hipStream_t stream) {
    const int*   eidx  = (const int*)d_in[0];
    const float* ef    = (const float*)d_in[1];
    const float* nlat  = (const float*)d_in[2];
    const float* nfeat = (const float*)d_in[3];
    const float* eeW1 = (const float*)d_in[4];
    const float* eeb1 = (const float*)d_in[5];
    const float* eeW2 = (const float*)d_in[6];
    const float* eeb2 = (const float*)d_in[7];
    const float* eeg  = (const float*)d_in[8];
    const float* eebe = (const float*)d_in[9];
    const float* peW1 = (const float*)d_in[10];
    const float* peb1 = (const float*)d_in[11];
    const float* peW2 = (const float*)d_in[12];
    const float* peb2 = (const float*)d_in[13];
    const float* peg  = (const float*)d_in[14];
    const float* pebe = (const float*)d_in[15];
    const float* pnW1 = (const float*)d_in[16];
    const float* pnb1 = (const float*)d_in[17];
    const float* pnW2 = (const float*)d_in[18];
    const float* pnb2 = (const float*)d_in[19];
    const float* png_ = (const float*)d_in[20];
    const float* pnbe = (const float*)d_in[21];
    const float* noW1 = (const float*)d_in[22];
    const float* nob1 = (const float*)d_in[23];
    const float* noW2 = (const float*)d_in[24];
    const float* nob2 = (const float*)d_in[25];

    char* ws = (char*)d_ws;
    float* seg = (float*)ws;                                  // 25,600,000 B
    float* cnt = (float*)(ws + 25600000);                     //    200,000 B
    u16* eeW2T = (u16*)(ws + 25800000);
    u16* peW1T = (u16*)(ws + 25800000 + 32768);
    u16* peW2T = (u16*)(ws + 25800000 + 32768 + 98304);
    u16* pnW1T = (u16*)(ws + 25800000 + 32768 + 98304 + 32768);
    u16* pnW2T = (u16*)(ws + 25800000 + 32768 + 98304 + 32768 + 65536);
    u16* noW1T = (u16*)(ws + 25800000 + 32768 + 98304 + 32768 + 65536 + 32768);

    hipMemsetAsync(ws, 0, 25800000, stream);

    k_prepT<<<64, 256, 0, stream>>>(eeW2, eeW2T, 128, 128);
    k_prepT<<<192, 256, 0, stream>>>(peW1, peW1T, 384, 128);
    k_prepT<<<64, 256, 0, stream>>>(peW2, peW2T, 128, 128);
    k_prepT<<<128, 256, 0, stream>>>(pnW1, pnW1T, 256, 128);
    k_prepT<<<64, 256, 0, stream>>>(pnW2, pnW2T, 128, 128);
    k_prepT<<<64, 256, 0, stream>>>(noW1, noW1T, 128, 128);

    float* outEL = (float*)d_out;
    float* outN  = outEL + (size_t)N_EDGES * HID;

    k_edge_ee<<<1024, 256, 0, stream>>>(ef, eeW1, eeb1, eeW2T, eeb2, eeg, eebe, outEL);
    k_edge_pe<<<768, 256, 0, stream>>>(eidx, nlat, nfeat, outEL, peW1T, peb1, peW2T, peb2,
                                       peg, pebe, seg, cnt);
    k_node<<<782, 256, 0, stream>>>(nfeat, seg, cnt, pnW1T, pnb1, pnW2T, pnb2, png_, pnbe,
                                    noW1T, nob1, noW2, nob2, outN);
}